// Round 1
// baseline (1326.821 us; speedup 1.0000x reference)
//
#include <hip/hip_runtime.h>

// ---------------------------------------------------------------------------
// GraphSAGE(2-layer, mean) x2 towers + LN + 3-layer MLP heads + X @ Y^T
// Strategy:
//   * CSR built on-device each call (count/scan/fill) -> pull-mode mean agg.
//   * All GEMMs via MFMA f32_16x16x32_f16 with fp16 hi/lo split (3 phases:
//     Ah*Bh + Ah*Bl + Al*Bh) for ~2^-21 per-stage relative error.
//   * Weights pre-split+transposed to [N,K] fp16-pairs per call.
//   * LN / aggregation in fp32; activations stored as fp16 pairs.
// ---------------------------------------------------------------------------

typedef _Float16 f16;
typedef __attribute__((ext_vector_type(8))) _Float16 f16x8;
typedef __attribute__((ext_vector_type(4))) _Float16 f16x4;
typedef __attribute__((ext_vector_type(8))) short s16x8;
typedef __attribute__((ext_vector_type(4))) float f32x4;

#define MN 16384
#define DN 8192
#define EMM 524288
#define EDD 262144

__device__ inline void splitf(float v, f16* __restrict__ h, f16* __restrict__ l) {
  f16 hh = (f16)v;
  *h = hh;
  *l = (f16)(v - (float)hh);
}

// ---------------- CSR build ----------------
__global__ void k_count(const int* __restrict__ dst, int E, int* __restrict__ cnt) {
  int i = blockIdx.x * blockDim.x + threadIdx.x;
  int stride = gridDim.x * blockDim.x;
  for (int e = i; e < E; e += stride) atomicAdd(&cnt[dst[e]], 1);
}

__global__ void k_scan(const int* __restrict__ cnt, int N, int* __restrict__ rp,
                       int* __restrict__ cur) {
  __shared__ int part[1024];
  int t = threadIdx.x;
  int per = N / 1024;
  int base = t * per;
  int s = 0;
  for (int i = 0; i < per; ++i) s += cnt[base + i];
  part[t] = s;
  __syncthreads();
  for (int off = 1; off < 1024; off <<= 1) {
    int v = (t >= off) ? part[t - off] : 0;
    __syncthreads();
    part[t] += v;
    __syncthreads();
  }
  int pre = (t == 0) ? 0 : part[t - 1];
  for (int i = 0; i < per; ++i) {
    int c = cnt[base + i];
    rp[base + i] = pre;
    cur[base + i] = pre;
    pre += c;
  }
  if (t == 1023) rp[N] = pre;
}

__global__ void k_fill(const int* __restrict__ src, const int* __restrict__ dst, int E,
                       int* __restrict__ cur, int* __restrict__ nbr) {
  int i = blockIdx.x * blockDim.x + threadIdx.x;
  int stride = gridDim.x * blockDim.x;
  for (int e = i; e < E; e += stride) {
    int p = atomicAdd(&cur[dst[e]], 1);
    nbr[p] = src[e];
  }
}

// ---------------- weight prep: split + transpose (+ stack Wl;Wr) ----------------
// Output Bt[N][K] fp16 hi/lo, Bt[n][k] = (k<K1 ? W1[k][n] : W2[k-K1][n])
__global__ void k_prep_w(const float* __restrict__ W1, const float* __restrict__ W2,
                         int K1, int K, int N, f16* __restrict__ Bh, f16* __restrict__ Bl) {
  int idx = blockIdx.x * blockDim.x + threadIdx.x;
  if (idx >= N * K) return;
  int n = idx / K, k = idx % K;
  float v = (k < K1) ? W1[k * N + n] : W2[(k - K1) * N + n];
  splitf(v, &Bh[idx], &Bl[idx]);
}

// ---------------- split fp32 matrix into fp16 pair at column offset ----------------
__global__ void k_split(const float* __restrict__ X, int total, int C, int ldo, int colOff,
                        f16* __restrict__ Oh, f16* __restrict__ Ol) {
  int idx = blockIdx.x * blockDim.x + threadIdx.x;
  if (idx >= total) return;
  int r = idx / C, c = idx % C;
  float v = X[idx];
  size_t o = (size_t)r * ldo + colOff + c;
  splitf(v, &Oh[o], &Ol[o]);
}

// ---------------- pull-mode mean aggregation (fp32 input) ----------------
template <int VPL>  // floats per lane; F = 64*VPL
__global__ void k_aggr_f32(const float* __restrict__ X, const int* __restrict__ rp,
                           const int* __restrict__ nbr, int Nn,
                           f16* __restrict__ Oh, f16* __restrict__ Ol, int ldo) {
  int node = blockIdx.x * (blockDim.x >> 6) + (threadIdx.x >> 6);
  if (node >= Nn) return;
  int lane = threadIdx.x & 63;
  int beg = rp[node], end = rp[node + 1];
  float acc[VPL] = {};
  const int F = VPL * 64;
  for (int j = beg; j < end; ++j) {
    int s = nbr[j];
    const float* p = X + (size_t)s * F + lane * VPL;
    if constexpr (VPL == 2) {
      float2 v = *reinterpret_cast<const float2*>(p);
      acc[0] += v.x; acc[1] += v.y;
    } else {
      float4 v = *reinterpret_cast<const float4*>(p);
      acc[0] += v.x; acc[1] += v.y; acc[2] += v.z; acc[3] += v.w;
    }
  }
  float inv = 1.0f / fmaxf((float)(end - beg), 1.0f);
  #pragma unroll
  for (int i = 0; i < VPL; ++i) {
    size_t o = (size_t)node * ldo + lane * VPL + i;
    splitf(acc[i] * inv, &Oh[o], &Ol[o]);
  }
}

// ---------------- pull-mode mean aggregation (fp16-pair input, F=256) ----------------
__global__ void k_aggr_pair(const f16* __restrict__ Xh, const f16* __restrict__ Xl, int ldx,
                            const int* __restrict__ rp, const int* __restrict__ nbr, int Nn,
                            f16* __restrict__ Oh, f16* __restrict__ Ol, int ldo) {
  int node = blockIdx.x * (blockDim.x >> 6) + (threadIdx.x >> 6);
  if (node >= Nn) return;
  int lane = threadIdx.x & 63;
  int beg = rp[node], end = rp[node + 1];
  float acc[4] = {};
  for (int j = beg; j < end; ++j) {
    int s = nbr[j];
    f16x4 vh = *reinterpret_cast<const f16x4*>(Xh + (size_t)s * ldx + lane * 4);
    f16x4 vl = *reinterpret_cast<const f16x4*>(Xl + (size_t)s * ldx + lane * 4);
    #pragma unroll
    for (int i = 0; i < 4; ++i) acc[i] += (float)vh[i] + (float)vl[i];
  }
  float inv = 1.0f / fmaxf((float)(end - beg), 1.0f);
  #pragma unroll
  for (int i = 0; i < 4; ++i) {
    size_t o = (size_t)node * ldo + lane * 4 + i;
    splitf(acc[i] * inv, &Oh[o], &Ol[o]);
  }
}

// ---------------- ReLU -> LayerNorm -> fp16-pair output ----------------
template <int VPL>  // N = 64*VPL (2 -> 128, 4 -> 256)
__global__ void k_ln(const float* __restrict__ C, int Mrows, int N,
                     const float* __restrict__ g, const float* __restrict__ b,
                     f16* __restrict__ Oh, f16* __restrict__ Ol, int ldo, int colOff) {
  int row = blockIdx.x * (blockDim.x >> 6) + (threadIdx.x >> 6);
  if (row >= Mrows) return;
  int lane = threadIdx.x & 63;
  float v[VPL];
  const float* src = C + (size_t)row * N + lane * VPL;
  if constexpr (VPL == 2) {
    float2 t = *reinterpret_cast<const float2*>(src);
    v[0] = t.x; v[1] = t.y;
  } else {
    float4 t = *reinterpret_cast<const float4*>(src);
    v[0] = t.x; v[1] = t.y; v[2] = t.z; v[3] = t.w;
  }
  float s = 0.f, ss = 0.f;
  #pragma unroll
  for (int i = 0; i < VPL; ++i) {
    v[i] = fmaxf(v[i], 0.0f);
    s += v[i];
    ss += v[i] * v[i];
  }
  #pragma unroll
  for (int off = 32; off > 0; off >>= 1) {
    s += __shfl_xor(s, off);
    ss += __shfl_xor(ss, off);
  }
  float mu = s / N;
  float var = ss / N - mu * mu;
  float rs = 1.0f / sqrtf(var + 1e-5f);
  #pragma unroll
  for (int i = 0; i < VPL; ++i) {
    int c = lane * VPL + i;
    float y = (v[i] - mu) * rs * g[c] + b[c];
    size_t o = (size_t)row * ldo + colOff + c;
    splitf(y, &Oh[o], &Ol[o]);
  }
}

// ---------------- fp16-pair GEMM: C = A @ B^T(+bias)(+relu), 3 error-comp phases ----
// A: [M, lda] fp16 pair (row-major), B: [N, K] fp16 pair (row-major, k-contig)
// EPI 0: Cf[row*N+col] = acc + bias   (bias may be null)
// EPI 1: Oh/Ol[row*ldo+col] = split(relu(acc + bias))
template <int EPI>
__global__ __launch_bounds__(256, 2) void k_gemm(
    const f16* __restrict__ Ah, const f16* __restrict__ Al, int lda,
    const f16* __restrict__ Bh, const f16* __restrict__ Bl,
    const float* __restrict__ bias, int N, int K,
    float* __restrict__ Cf, f16* __restrict__ Oh, f16* __restrict__ Ol, int ldo) {
  __shared__ f16 As[128][72];  // 144B row stride (16B aligned, conflict-benign)
  __shared__ f16 Bs[64][72];
  const int row0 = blockIdx.y * 128;
  const int col0 = blockIdx.x * 64;
  const int t = threadIdx.x, lane = t & 63, w = t >> 6;
  const int wr = w >> 1, wc = w & 1;  // wave tile: 64 rows x 32 cols
  f32x4 acc[4][2] = {};
  for (int ph = 0; ph < 3; ++ph) {
    const f16* A = (ph < 2) ? Ah : Al;
    const f16* B = (ph == 1) ? Bl : Bh;
    for (int kb = 0; kb < K; kb += 64) {
      __syncthreads();
      #pragma unroll
      for (int c = 0; c < 4; ++c) {  // stage A: 128 rows x 64 k (16KB)
        int idx = t + c * 256, r = idx >> 3, ck = idx & 7;
        s16x8 v = *reinterpret_cast<const s16x8*>(A + (size_t)(row0 + r) * lda + kb + ck * 8);
        *reinterpret_cast<s16x8*>(&As[r][ck * 8]) = v;
      }
      #pragma unroll
      for (int c = 0; c < 2; ++c) {  // stage B: 64 n-rows x 64 k (8KB)
        int idx = t + c * 256, r = idx >> 3, ck = idx & 7;
        s16x8 v = *reinterpret_cast<const s16x8*>(B + (size_t)(col0 + r) * K + kb + ck * 8);
        *reinterpret_cast<s16x8*>(&Bs[r][ck * 8]) = v;
      }
      __syncthreads();
      #pragma unroll
      for (int kk = 0; kk < 2; ++kk) {
        f16x8 bfrag[2];
        #pragma unroll
        for (int n = 0; n < 2; ++n)
          bfrag[n] = *reinterpret_cast<const f16x8*>(
              &Bs[wc * 32 + n * 16 + (lane & 15)][kk * 32 + (lane >> 4) * 8]);
        #pragma unroll
        for (int m = 0; m < 4; ++m) {
          f16x8 afrag = *reinterpret_cast<const f16x8*>(
              &As[wr * 64 + m * 16 + (lane & 15)][kk * 32 + (lane >> 4) * 8]);
          #pragma unroll
          for (int n = 0; n < 2; ++n)
            acc[m][n] = __builtin_amdgcn_mfma_f32_16x16x32_f16(afrag, bfrag[n], acc[m][n], 0, 0, 0);
        }
      }
    }
  }
  // epilogue: D row=(lane>>4)*4+q, col=lane&15 (m89-verified layout)
  #pragma unroll
  for (int m = 0; m < 4; ++m) {
    #pragma unroll
    for (int n = 0; n < 2; ++n) {
      int col = col0 + wc * 32 + n * 16 + (lane & 15);
      float bv = bias ? bias[col] : 0.0f;
      #pragma unroll
      for (int q = 0; q < 4; ++q) {
        int row = row0 + wr * 64 + m * 16 + (lane >> 4) * 4 + q;
        float v = acc[m][n][q] + bv;
        if constexpr (EPI == 0) {
          Cf[(size_t)row * N + col] = v;
        } else {
          v = fmaxf(v, 0.0f);
          size_t o = (size_t)row * ldo + col;
          splitf(v, &Oh[o], &Ol[o]);
        }
      }
    }
  }
}

// ---------------------------------------------------------------------------
extern "C" void kernel_launch(void* const* d_in, const int* in_sizes, int n_in,
                              void* d_out, int out_size, void* d_ws, size_t ws_size,
                              hipStream_t stream) {
  (void)in_sizes; (void)n_in; (void)out_size; (void)ws_size;
  const float* x_m = (const float*)d_in[0];
  const float* x_d = (const float*)d_in[1];
  const int* mm = (const int*)d_in[2];
  const int* dd = (const int*)d_in[3];
  const float* sx1_Wl = (const float*)d_in[4];
  const float* sx1_bl = (const float*)d_in[5];
  const float* sx1_Wr = (const float*)d_in[6];
  const float* sx2_Wl = (const float*)d_in[7];
  const float* sx2_bl = (const float*)d_in[8];
  const float* sx2_Wr = (const float*)d_in[9];
  const float* sy1_Wl = (const float*)d_in[10];
  const float* sy1_bl = (const float*)d_in[11];
  const float* sy1_Wr = (const float*)d_in[12];
  const float* sy2_Wl = (const float*)d_in[13];
  const float* sy2_bl = (const float*)d_in[14];
  const float* sy2_Wr = (const float*)d_in[15];
  const float* nx1_g = (const float*)d_in[16];
  const float* nx1_b = (const float*)d_in[17];
  const float* nx2_g = (const float*)d_in[18];
  const float* nx2_b = (const float*)d_in[19];
  const float* ny1_g = (const float*)d_in[20];
  const float* ny1_b = (const float*)d_in[21];
  const float* ny2_g = (const float*)d_in[22];
  const float* ny2_b = (const float*)d_in[23];
  const float* lx1_W = (const float*)d_in[24];
  const float* lx1_b = (const float*)d_in[25];
  const float* lx2_W = (const float*)d_in[26];
  const float* lx2_b = (const float*)d_in[27];
  const float* lx3_W = (const float*)d_in[28];
  const float* lx3_b = (const float*)d_in[29];
  const float* ly1_W = (const float*)d_in[30];
  const float* ly1_b = (const float*)d_in[31];
  const float* ly2_W = (const float*)d_in[32];
  const float* ly2_b = (const float*)d_in[33];
  const float* ly3_W = (const float*)d_in[34];
  const float* ly3_b = (const float*)d_in[35];

  char* p = (char*)d_ws;
  auto alloc = [&](size_t bytes) -> void* {
    void* r = (void*)p;
    p += (bytes + 255) & ~(size_t)255;
    return r;
  };

  int* cnt_m = (int*)alloc(MN * 4);
  int* rp_m  = (int*)alloc((MN + 1) * 4);
  int* cur_m = (int*)alloc(MN * 4);
  int* nbr_m = (int*)alloc((size_t)EMM * 4);
  int* cnt_d = (int*)alloc(DN * 4);
  int* rp_d  = (int*)alloc((DN + 1) * 4);
  int* cur_d = (int*)alloc(DN * 4);
  int* nbr_d = (int*)alloc((size_t)EDD * 4);

  f16 *Bsx1h = (f16*)alloc(256 * 256 * 2), *Bsx1l = (f16*)alloc(256 * 256 * 2);
  f16 *Bsx2h = (f16*)alloc(128 * 512 * 2), *Bsx2l = (f16*)alloc(128 * 512 * 2);
  f16 *Bsy1h = (f16*)alloc(256 * 256 * 2), *Bsy1l = (f16*)alloc(256 * 256 * 2);
  f16 *Bsy2h = (f16*)alloc(128 * 512 * 2), *Bsy2l = (f16*)alloc(128 * 512 * 2);
  f16 *Blx1h = (f16*)alloc(256 * 128 * 2), *Blx1l = (f16*)alloc(256 * 128 * 2);
  f16 *Blx2h = (f16*)alloc(128 * 256 * 2), *Blx2l = (f16*)alloc(128 * 256 * 2);
  f16 *Blx3h = (f16*)alloc(64 * 128 * 2),  *Blx3l = (f16*)alloc(64 * 128 * 2);
  f16 *Bly1h = (f16*)alloc(256 * 128 * 2), *Bly1l = (f16*)alloc(256 * 128 * 2);
  f16 *Bly2h = (f16*)alloc(128 * 256 * 2), *Bly2l = (f16*)alloc(128 * 256 * 2);
  f16 *Bly3h = (f16*)alloc(64 * 128 * 2),  *Bly3l = (f16*)alloc(64 * 128 * 2);

  f16 *A1h = (f16*)alloc((size_t)MN * 256 * 2), *A1l = (f16*)alloc((size_t)MN * 256 * 2);
  f16 *A2h = (f16*)alloc((size_t)MN * 512 * 2), *A2l = (f16*)alloc((size_t)MN * 512 * 2);
  float* Cbuf = (float*)alloc((size_t)MN * 256 * 4);
  f16 *H1h = (f16*)alloc((size_t)MN * 128 * 2), *H1l = (f16*)alloc((size_t)MN * 128 * 2);
  f16 *H2h = (f16*)alloc((size_t)MN * 256 * 2), *H2l = (f16*)alloc((size_t)MN * 256 * 2);
  f16 *H3h = (f16*)alloc((size_t)MN * 128 * 2), *H3l = (f16*)alloc((size_t)MN * 128 * 2);
  f16 *Xfh = (f16*)alloc((size_t)MN * 64 * 2),  *Xfl = (f16*)alloc((size_t)MN * 64 * 2);
  f16 *Yfh = (f16*)alloc((size_t)DN * 64 * 2),  *Yfl = (f16*)alloc((size_t)DN * 64 * 2);

  // ---- CSR for both graphs ----
  hipMemsetAsync(cnt_m, 0, MN * 4, stream);
  hipMemsetAsync(cnt_d, 0, DN * 4, stream);
  k_count<<<1024, 256, 0, stream>>>(mm + EMM, EMM, cnt_m);
  k_count<<<512, 256, 0, stream>>>(dd + EDD, EDD, cnt_d);
  k_scan<<<1, 1024, 0, stream>>>(cnt_m, MN, rp_m, cur_m);
  k_scan<<<1, 1024, 0, stream>>>(cnt_d, DN, rp_d, cur_d);
  k_fill<<<1024, 256, 0, stream>>>(mm, mm + EMM, EMM, cur_m, nbr_m);
  k_fill<<<512, 256, 0, stream>>>(dd, dd + EDD, EDD, cur_d, nbr_d);

  // ---- weight prep ----
  k_prep_w<<<(256 * 256 + 255) / 256, 256, 0, stream>>>(sx1_Wl, sx1_Wr, 128, 256, 256, Bsx1h, Bsx1l);
  k_prep_w<<<(128 * 512 + 255) / 256, 256, 0, stream>>>(sx2_Wl, sx2_Wr, 256, 512, 128, Bsx2h, Bsx2l);
  k_prep_w<<<(256 * 256 + 255) / 256, 256, 0, stream>>>(sy1_Wl, sy1_Wr, 128, 256, 256, Bsy1h, Bsy1l);
  k_prep_w<<<(128 * 512 + 255) / 256, 256, 0, stream>>>(sy2_Wl, sy2_Wr, 256, 512, 128, Bsy2h, Bsy2l);
  k_prep_w<<<(256 * 128 + 255) / 256, 256, 0, stream>>>(lx1_W, lx1_W, 128, 128, 256, Blx1h, Blx1l);
  k_prep_w<<<(128 * 256 + 255) / 256, 256, 0, stream>>>(lx2_W, lx2_W, 256, 256, 128, Blx2h, Blx2l);
  k_prep_w<<<(64 * 128 + 255) / 256, 256, 0, stream>>>(lx3_W, lx3_W, 128, 128, 64, Blx3h, Blx3l);
  k_prep_w<<<(256 * 128 + 255) / 256, 256, 0, stream>>>(ly1_W, ly1_W, 128, 128, 256, Bly1h, Bly1l);
  k_prep_w<<<(128 * 256 + 255) / 256, 256, 0, stream>>>(ly2_W, ly2_W, 256, 256, 128, Bly2h, Bly2l);
  k_prep_w<<<(64 * 128 + 255) / 256, 256, 0, stream>>>(ly3_W, ly3_W, 128, 128, 64, Bly3h, Bly3l);

  // ---- x tower ----
  k_split<<<(MN * 128 + 255) / 256, 256, 0, stream>>>(x_m, MN * 128, 128, 256, 128, A1h, A1l);
  k_aggr_f32<2><<<MN / 4, 256, 0, stream>>>(x_m, rp_m, nbr_m, MN, A1h, A1l, 256);
  k_gemm<0><<<dim3(4, MN / 128), 256, 0, stream>>>(A1h, A1l, 256, Bsx1h, Bsx1l, sx1_bl, 256, 256, Cbuf, nullptr, nullptr, 0);
  k_ln<4><<<MN / 4, 256, 0, stream>>>(Cbuf, MN, 256, nx1_g, nx1_b, A2h, A2l, 512, 256);
  k_aggr_pair<<<MN / 4, 256, 0, stream>>>(A2h + 256, A2l + 256, 512, rp_m, nbr_m, MN, A2h, A2l, 512);
  k_gemm<0><<<dim3(2, MN / 128), 256, 0, stream>>>(A2h, A2l, 512, Bsx2h, Bsx2l, sx2_bl, 128, 512, Cbuf, nullptr, nullptr, 0);
  k_ln<2><<<MN / 4, 256, 0, stream>>>(Cbuf, MN, 128, nx2_g, nx2_b, H1h, H1l, 128, 0);
  // x head
  k_gemm<1><<<dim3(4, MN / 128), 256, 0, stream>>>(H1h, H1l, 128, Blx1h, Blx1l, lx1_b, 256, 128, nullptr, H2h, H2l, 256);
  k_gemm<1><<<dim3(2, MN / 128), 256, 0, stream>>>(H2h, H2l, 256, Blx2h, Blx2l, lx2_b, 128, 256, nullptr, H3h, H3l, 128);
  k_gemm<1><<<dim3(1, MN / 128), 256, 0, stream>>>(H3h, H3l, 128, Blx3h, Blx3l, lx3_b, 64, 128, nullptr, Xfh, Xfl, 64);

  // ---- y tower (reuses A1/A2/Cbuf/H1-3) ----
  k_split<<<(DN * 128 + 255) / 256, 256, 0, stream>>>(x_d, DN * 128, 128, 256, 128, A1h, A1l);
  k_aggr_f32<2><<<DN / 4, 256, 0, stream>>>(x_d, rp_d, nbr_d, DN, A1h, A1l, 256);
  k_gemm<0><<<dim3(4, DN / 128), 256, 0, stream>>>(A1h, A1l, 256, Bsy1h, Bsy1l, sy1_bl, 256, 256, Cbuf, nullptr, nullptr, 0);
  k_ln<4><<<DN / 4, 256, 0, stream>>>(Cbuf, DN, 256, ny1_g, ny1_b, A2h, A2l, 512, 256);
  k_aggr_pair<<<DN / 4, 256, 0, stream>>>(A2h + 256, A2l + 256, 512, rp_d, nbr_d, DN, A2h, A2l, 512);
  k_gemm<0><<<dim3(2, DN / 128), 256, 0, stream>>>(A2h, A2l, 512, Bsy2h, Bsy2l, sy2_bl, 128, 512, Cbuf, nullptr, nullptr, 0);
  k_ln<2><<<DN / 4, 256, 0, stream>>>(Cbuf, DN, 128, ny2_g, ny2_b, H1h, H1l, 128, 0);
  // y head
  k_gemm<1><<<dim3(4, DN / 128), 256, 0, stream>>>(H1h, H1l, 128, Bly1h, Bly1l, ly1_b, 256, 128, nullptr, H2h, H2l, 256);
  k_gemm<1><<<dim3(2, DN / 128), 256, 0, stream>>>(H2h, H2l, 256, Bly2h, Bly2l, ly2_b, 128, 256, nullptr, H3h, H3l, 128);
  k_gemm<1><<<dim3(1, DN / 128), 256, 0, stream>>>(H3h, H3l, 128, Bly3h, Bly3l, ly3_b, 64, 128, nullptr, Yfh, Yfl, 64);

  // ---- final: out[M,D] = Xf @ Yf^T  (Yf [8192,64] is already the [N,K] B layout) ----
  k_gemm<0><<<dim3(DN / 64, MN / 128), 256, 0, stream>>>(Xfh, Xfl, 64, Yfh, Yfl, nullptr, DN, 64, (float*)d_out, nullptr, nullptr, 0);
}